// Round 2
// baseline (18246.182 us; speedup 1.0000x reference)
//
#include <hip/hip_runtime.h>
#include <hip/hip_bf16.h>
#include <math.h>

typedef __hip_bfloat16 bf;

__device__ __forceinline__ float bf2f(bf v) { return __bfloat162float(v); }
__device__ __forceinline__ bf f2bf(float v) { return __float2bfloat16(v); }

// ---------------------------------------------------------------------------
// Direct 3x3 conv, pad 1, stride s, ReLU. Input type templated (f32 for cts,
// bf16 elsewhere); output bf16. Two input pointers support channel concat.
// ---------------------------------------------------------------------------
template <typename TIN>
__global__ void conv3x3_relu(const TIN* __restrict__ inA, const TIN* __restrict__ inB,
                             int CiA, int Ci,
                             const float* __restrict__ Wt, const float* __restrict__ Bias,
                             bf* __restrict__ out,
                             int N, int Hi, int Wi, int Co, int Ho, int Wo, int stride)
{
    int tid = blockIdx.x * blockDim.x + threadIdx.x;
    int total = N * Co * Ho * Wo;
    if (tid >= total) return;
    int x = tid % Wo;
    int tmp = tid / Wo;
    int y = tmp % Ho; tmp /= Ho;
    int o = tmp % Co;
    int n = tmp / Co;

    float acc = Bias[o];
    int y0 = y * stride - 1, x0 = x * stride - 1;
    int CiB = Ci - CiA;
    for (int ci = 0; ci < Ci; ++ci) {
        const TIN* src;
        if (ci < CiA) src = inA + (size_t)(n * CiA + ci) * Hi * Wi;
        else          src = inB + (size_t)(n * CiB + (ci - CiA)) * Hi * Wi;
        const float* wp = Wt + (size_t)(o * Ci + ci) * 9;
        #pragma unroll
        for (int ky = 0; ky < 3; ++ky) {
            int iy = y0 + ky;
            if ((unsigned)iy >= (unsigned)Hi) continue;
            const TIN* row = src + (size_t)iy * Wi;
            #pragma unroll
            for (int kx = 0; kx < 3; ++kx) {
                int ix = x0 + kx;
                if ((unsigned)ix < (unsigned)Wi)
                    acc = fmaf((float)row[ix], wp[ky * 3 + kx], acc);
            }
        }
    }
    out[tid] = f2bf(fmaxf(acc, 0.0f));
}

// ---------------------------------------------------------------------------
// Transposed conv (k=3, s=2, p=1, op=1) as lhs-dilated conv, ReLU. bf16 io.
// ---------------------------------------------------------------------------
__global__ void convt3x3_relu(const bf* __restrict__ inA, const bf* __restrict__ inB,
                              int CiA, int Ci,
                              const float* __restrict__ Wt, const float* __restrict__ Bias,
                              bf* __restrict__ out,
                              int N, int Hi, int Wi, int Co, int Ho, int Wo)
{
    int tid = blockIdx.x * blockDim.x + threadIdx.x;
    int total = N * Co * Ho * Wo;
    if (tid >= total) return;
    int x = tid % Wo;
    int tmp = tid / Wo;
    int y = tmp % Ho; tmp /= Ho;
    int o = tmp % Co;
    int n = tmp / Co;

    float acc = Bias[o];
    int CiB = Ci - CiA;
    for (int ci = 0; ci < Ci; ++ci) {
        const bf* src;
        if (ci < CiA) src = inA + (size_t)(n * CiA + ci) * Hi * Wi;
        else          src = inB + (size_t)(n * CiB + (ci - CiA)) * Hi * Wi;
        const float* wp = Wt + (size_t)(o * Ci + ci) * 9;
        #pragma unroll
        for (int ky = 0; ky < 3; ++ky) {
            int dy = y + ky - 1;
            if (dy & 1) continue;
            int iy = dy >> 1;
            if ((unsigned)iy >= (unsigned)Hi) continue;
            const bf* row = src + (size_t)iy * Wi;
            #pragma unroll
            for (int kx = 0; kx < 3; ++kx) {
                int dx = x + kx - 1;
                if (dx & 1) continue;
                int ix = dx >> 1;
                if ((unsigned)ix < (unsigned)Wi)
                    acc = fmaf(bf2f(row[ix]), wp[ky * 3 + kx], acc);
            }
        }
    }
    out[tid] = f2bf(fmaxf(acc, 0.0f));
}

// ---------------------------------------------------------------------------
// Pairwise Gram partials over 256-feature chunks. Deterministic, no atomics.
// ---------------------------------------------------------------------------
#define SCH 256
__global__ void sim_partial(const bf* __restrict__ f, float* __restrict__ part, int KTOT)
{
    __shared__ float tile[32][SCH + 1];
    int c = blockIdx.x;
    int t = threadIdx.x;
    int k0 = c * SCH;
    for (int r = 0; r < 32; ++r)
        tile[r][t] = bf2f(f[(size_t)r * KTOT + k0 + t]);
    __syncthreads();
    int i = t >> 3;
    int j0 = (t & 7) * 4;
    float a0 = 0.f, a1 = 0.f, a2 = 0.f, a3 = 0.f;
    for (int k = 0; k < SCH; ++k) {
        float fi = tile[i][k];
        a0 = fmaf(fi, tile[j0 + 0][k], a0);
        a1 = fmaf(fi, tile[j0 + 1][k], a1);
        a2 = fmaf(fi, tile[j0 + 2][k], a2);
        a3 = fmaf(fi, tile[j0 + 3][k], a3);
    }
    float* dst = part + (size_t)c * 1024 + i * 32 + j0;
    dst[0] = a0; dst[1] = a1; dst[2] = a2; dst[3] = a3;
}

__global__ void sim_reduce(const float* __restrict__ part, float* __restrict__ sim,
                           int nchunks, int total)
{
    int t = blockIdx.x * blockDim.x + threadIdx.x;
    if (t >= total) return;
    float s = 0.f;
    for (int c = 0; c < nchunks; ++c) s += part[(size_t)c * 1024 + t];
    sim[t] = s;
}

// ---------------------------------------------------------------------------
// Cosine sim + group mask + top-3 (strict >, lowest index wins ties).
// ---------------------------------------------------------------------------
__global__ void topk_kernel(const float* __restrict__ sim, const int* __restrict__ prange,
                            int* __restrict__ idx, int N)
{
    int i = threadIdx.x;
    if (i >= N) return;
    float nm_i = fmaxf(sqrtf(sim[i * N + i]), 1e-8f);
    int p0 = prange[0], p1 = prange[1];
    int gi = (i >= p0) + (i >= p1);
    float vals[32];
    for (int j = 0; j < N; ++j) {
        int gj = (j >= p0) + (j >= p1);
        if (j == i || gj != gi) { vals[j] = -1e30f; continue; }
        float nm_j = fmaxf(sqrtf(sim[j * N + j]), 1e-8f);
        vals[j] = sim[i * N + j] / (nm_i * nm_j);
    }
    for (int k = 0; k < 3; ++k) {
        float best = -2e30f; int bj = 0;
        for (int j = 0; j < N; ++j)
            if (vals[j] > best) { best = vals[j]; bj = j; }
        idx[i * 3 + k] = bj;
        vals[bj] = -1e30f;
    }
}

// ---------------------------------------------------------------------------
// KNN aggregation: agg = mean_k relu(conv3x3(u3[idx[k]], w_ga))
// ---------------------------------------------------------------------------
__global__ void knn_agg(const bf* __restrict__ u3, const int* __restrict__ idx,
                        const float* __restrict__ Wg, const float* __restrict__ Bg,
                        bf* __restrict__ agg, int N)
{
    int tid = blockIdx.x * blockDim.x + threadIdx.x;
    int total = N * 16 * 256 * 256;
    if (tid >= total) return;
    int x = tid & 255;
    int tmp = tid >> 8;
    int y = tmp & 255; tmp >>= 8;
    int o = tmp & 15;
    int n = tmp >> 4;

    float sum = 0.f;
    for (int k = 0; k < 3; ++k) {
        int nb = idx[n * 3 + k];
        float acc = Bg[o];
        for (int i = 0; i < 16; ++i) {
            const bf* src = u3 + ((size_t)(nb * 16 + i) << 16);
            const float* wp = Wg + (o * 16 + i) * 9;
            #pragma unroll
            for (int ky = 0; ky < 3; ++ky) {
                int iy = y + ky - 1;
                if ((unsigned)iy >= 256u) continue;
                const bf* row = src + (iy << 8);
                #pragma unroll
                for (int kx = 0; kx < 3; ++kx) {
                    int ix = x + kx - 1;
                    if ((unsigned)ix < 256u)
                        acc = fmaf(bf2f(row[ix]), wp[ky * 3 + kx], acc);
                }
            }
        }
        sum += fmaxf(acc, 0.f);
    }
    agg[tid] = f2bf(sum * (1.f / 3.f));
}

// ---------------------------------------------------------------------------
// Fused epilogue: gnn conv (16 ch from [u3|agg]), d1 recompute from cts,
// dense 32->2, softmax, NCHW f32 store.
// ---------------------------------------------------------------------------
__global__ void final_fused(const float* __restrict__ cts, const bf* __restrict__ u3,
                            const bf* __restrict__ agg,
                            const float* __restrict__ w_d1, const float* __restrict__ b_d1,
                            const float* __restrict__ w_gu, const float* __restrict__ b_gu,
                            const float* __restrict__ w_de, const float* __restrict__ b_de,
                            float* __restrict__ out, int N)
{
    __shared__ float sW[16 * 32 * 9];
    __shared__ float sDe[64];
    for (int i = threadIdx.x; i < 16 * 32 * 9; i += blockDim.x) sW[i] = w_gu[i];
    if (threadIdx.x < 64) sDe[threadIdx.x] = w_de[threadIdx.x];
    __syncthreads();

    int tid = blockIdx.x * blockDim.x + threadIdx.x;
    int total = N * 256 * 256;
    if (tid >= total) return;
    int x = tid & 255;
    int y = (tid >> 8) & 255;
    int n = tid >> 16;

    float g[16];
    #pragma unroll
    for (int c = 0; c < 16; ++c) g[c] = b_gu[c];

    for (int i = 0; i < 32; ++i) {
        const bf* src = (i < 16) ? u3 + ((size_t)(n * 16 + i) << 16)
                                 : agg + ((size_t)(n * 16 + (i - 16)) << 16);
        float tap[9];
        #pragma unroll
        for (int ky = 0; ky < 3; ++ky) {
            int iy = y + ky - 1;
            #pragma unroll
            for (int kx = 0; kx < 3; ++kx) {
                int ix = x + kx - 1;
                tap[ky * 3 + kx] = ((unsigned)iy < 256u && (unsigned)ix < 256u)
                                   ? bf2f(src[(iy << 8) + ix]) : 0.f;
            }
        }
        #pragma unroll
        for (int c = 0; c < 16; ++c) {
            const float* wp = &sW[(c * 32 + i) * 9];
            #pragma unroll
            for (int t9 = 0; t9 < 9; ++t9) g[c] = fmaf(tap[t9], wp[t9], g[c]);
        }
    }

    float l0 = b_de[0], l1 = b_de[1];
    #pragma unroll
    for (int c = 0; c < 16; ++c) {
        float v = fmaxf(g[c], 0.f);
        l0 = fmaf(v, sDe[c * 2 + 0], l0);
        l1 = fmaf(v, sDe[c * 2 + 1], l1);
    }

    const float* csrc = cts + ((size_t)n << 16);
    float ct[9];
    #pragma unroll
    for (int ky = 0; ky < 3; ++ky) {
        int iy = y + ky - 1;
        #pragma unroll
        for (int kx = 0; kx < 3; ++kx) {
            int ix = x + kx - 1;
            ct[ky * 3 + kx] = ((unsigned)iy < 256u && (unsigned)ix < 256u)
                              ? csrc[(iy << 8) + ix] : 0.f;
        }
    }
    #pragma unroll
    for (int c = 0; c < 16; ++c) {
        float acc = b_d1[c];
        const float* wp = w_d1 + c * 9;
        #pragma unroll
        for (int t9 = 0; t9 < 9; ++t9) acc = fmaf(ct[t9], wp[t9], acc);
        float v = fmaxf(acc, 0.f);
        l0 = fmaf(v, sDe[(16 + c) * 2 + 0], l0);
        l1 = fmaf(v, sDe[(16 + c) * 2 + 1], l1);
    }

    float m = fmaxf(l0, l1);
    float e0 = expf(l0 - m), e1 = expf(l1 - m);
    float inv = 1.f / (e0 + e1);
    size_t base = ((size_t)n * 2) << 16;
    out[base + (y << 8) + x] = e0 * inv;
    out[base + (1 << 16) + (y << 8) + x] = e1 * inv;
}

// ---------------------------------------------------------------------------

extern "C" void kernel_launch(void* const* d_in, const int* in_sizes, int n_in,
                              void* d_out, int out_size, void* d_ws, size_t ws_size,
                              hipStream_t stream)
{
    const float* cts  = (const float*)d_in[0];
    const int*   prng = (const int*)d_in[1];
    const float* w_d1 = (const float*)d_in[2];  const float* b_d1 = (const float*)d_in[3];
    const float* w_d2 = (const float*)d_in[4];  const float* b_d2 = (const float*)d_in[5];
    const float* w_d3 = (const float*)d_in[6];  const float* b_d3 = (const float*)d_in[7];
    const float* w_d4 = (const float*)d_in[8];  const float* b_d4 = (const float*)d_in[9];
    const float* w_u1 = (const float*)d_in[10]; const float* b_u1 = (const float*)d_in[11];
    const float* w_u2 = (const float*)d_in[12]; const float* b_u2 = (const float*)d_in[13];
    const float* w_u3 = (const float*)d_in[14]; const float* b_u3 = (const float*)d_in[15];
    const float* w_ga = (const float*)d_in[16]; const float* b_ga = (const float*)d_in[17];
    const float* w_gu = (const float*)d_in[18]; const float* b_gu = (const float*)d_in[19];
    const float* w_de = (const float*)d_in[20]; const float* b_de = (const float*)d_in[21];

    const int H = 256, Wd = 256;
    const int N = in_sizes[0] / (H * Wd);   // 32

    // ---- workspace layout (bytes), bf16 feature maps, lifetime reuse ----
    // U3  [67,108,864 B]  : u3 (persists to end)
    // AGG [67,108,864 B]  : d1 -> u1 [0:16.7M] + u2 [16.7M:50.3M] -> agg
    // T1  [33,554,432 B]  : d2 -> simp (16.7MB f32) + sim
    // T2  [33,554,432 B]  : d3 [0:16.7M] + d4 [16.7M:25.2M] -> idx
    // total 192 MiB
    char* wsb = (char*)d_ws;
    bf* U3  = (bf*)(wsb);
    bf* AGG = (bf*)(wsb + 67108864);
    bf* T1  = (bf*)(wsb + 134217728);
    bf* T2  = (bf*)(wsb + 167772160);

    bf* d1 = AGG;
    bf* d2 = T1;
    bf* d3 = T2;
    bf* d4 = (bf*)(wsb + 167772160 + 16777216);
    bf* u1 = AGG;
    bf* u2 = (bf*)(wsb + 67108864 + 16777216);
    bf* u3 = U3;
    float* simp = (float*)T1;                 // 4096*1024 f32 = 16.7 MB
    float* sim  = (float*)(wsb + 134217728 + 16777216);
    int*   idx  = (int*)T2;
    bf* agg = AGG;

    const int KTOT = 16 * H * Wd;             // 1,048,576
    const int NCH  = KTOT / SCH;              // 4096

    size_t szA = (size_t)N * 16 * H * Wd;
    size_t szB = (size_t)N * 32 * (H/2) * (Wd/2);
    size_t szC = (size_t)N * 64 * (H/4) * (Wd/4);
    size_t szD = (size_t)N * 128 * (H/8) * (Wd/8);
    auto nb = [](size_t total) { return (unsigned)((total + 255) / 256); };

    // encoder
    conv3x3_relu<float><<<nb(szA), 256, 0, stream>>>(cts, nullptr, 1, 1, w_d1, b_d1, d1,
                                                     N, 256, 256, 16, 256, 256, 1);
    conv3x3_relu<bf><<<nb(szB), 256, 0, stream>>>(d1, nullptr, 16, 16, w_d2, b_d2, d2,
                                                  N, 256, 256, 32, 128, 128, 2);
    conv3x3_relu<bf><<<nb(szC), 256, 0, stream>>>(d2, nullptr, 32, 32, w_d3, b_d3, d3,
                                                  N, 128, 128, 64, 64, 64, 2);
    conv3x3_relu<bf><<<nb(szD), 256, 0, stream>>>(d3, nullptr, 64, 64, w_d4, b_d4, d4,
                                                  N, 64, 64, 128, 32, 32, 2);
    // decoder
    convt3x3_relu<<<nb(szC), 256, 0, stream>>>(d4, nullptr, 128, 128, w_u1, b_u1, u1,
                                               N, 32, 32, 64, 64, 64);
    convt3x3_relu<<<nb(szB), 256, 0, stream>>>(u1, d3, 64, 128, w_u2, b_u2, u2,
                                               N, 64, 64, 32, 128, 128);
    convt3x3_relu<<<nb(szA), 256, 0, stream>>>(u2, d2, 32, 64, w_u3, b_u3, u3,
                                               N, 128, 128, 16, 256, 256);
    // cosine similarity + top-3  (scratch overwrites dead d2/d3/d4)
    sim_partial<<<NCH, 256, 0, stream>>>(u3, simp, KTOT);
    sim_reduce<<<nb(N * N), 256, 0, stream>>>(simp, sim, NCH, N * N);
    topk_kernel<<<1, 64, 0, stream>>>(sim, prng, idx, N);
    // knn conv + mean  (agg overwrites dead d1/u1/u2)
    knn_agg<<<nb(szA), 256, 0, stream>>>(u3, idx, w_ga, b_ga, agg, N);
    // fused gnn conv + d1 recompute + dense + softmax
    final_fused<<<nb((size_t)N * H * Wd), 256, 0, stream>>>(
        cts, u3, agg, w_d1, b_d1, w_gu, b_gu, w_de, b_de, (float*)d_out, N);
}

// Round 3
// 3655.637 us; speedup vs baseline: 4.9912x; 4.9912x over previous
//
#include <hip/hip_runtime.h>
#include <hip/hip_bf16.h>
#include <math.h>

typedef __hip_bfloat16 bf;

__device__ __forceinline__ float bf2f(bf v) { return __bfloat162float(v); }
__device__ __forceinline__ bf f2bf(float v) { return __float2bfloat16(v); }

// ===========================================================================
// Tiled direct 3x3 conv, pad 1, stride STRIDE, ReLU.
// Block = 256 threads = 16x16 output tile. blockIdx.x = tile, .y = n,
// .z = output-channel group of 16. Input staged in LDS in chunks of 8 ch.
// Two input pointers support channel concat. Output bf16.
// ===========================================================================
template <typename TIN, int STRIDE>
__global__ __launch_bounds__(256)
void conv_tiled(const TIN* __restrict__ inA, const TIN* __restrict__ inB,
                int CiA, int Ci,
                const float* __restrict__ Wt, const float* __restrict__ Bias,
                bf* __restrict__ out,
                int N, int Hi, int Wi, int Co, int Ho, int Wo, int tilesX)
{
    constexpr int TS = 16;
    constexpr int IH = (TS - 1) * STRIDE + 3;          // 18 or 33
    constexpr int IWP = (IH % 2 == 0) ? IH + 1 : IH;   // 19 or 33
    constexpr int CHUNK = 8;

    __shared__ TIN  sIn[CHUNK * IH * IWP];
    __shared__ float sW[CHUNK * 144];                  // [ci][t9][co16]

    int tile = blockIdx.x;
    int tx0 = (tile % tilesX) * TS, ty0 = (tile / tilesX) * TS;
    int n = blockIdx.y;
    int cog0 = blockIdx.z * 16;
    int t = threadIdx.x;
    int tx = t & 15, ty = t >> 4;
    int CiB = Ci - CiA;

    float acc[16];
    #pragma unroll
    for (int c = 0; c < 16; ++c) acc[c] = Bias[cog0 + c];

    for (int cb = 0; cb < Ci; cb += CHUNK) {
        int cn = (Ci - cb < CHUNK) ? (Ci - cb) : CHUNK;
        // stage input chunk (+halo), zero-padded
        for (int e = t; e < cn * IH * IH; e += 256) {
            int ci = e / (IH * IH);
            int rem = e % (IH * IH);
            int py = rem / IH, px = rem % IH;
            int iy = ty0 * STRIDE - 1 + py;
            int ix = tx0 * STRIDE - 1 + px;
            int gci = cb + ci;
            const TIN* src = (gci < CiA)
                ? inA + (size_t)(n * CiA + gci) * Hi * Wi
                : inB + (size_t)(n * CiB + gci - CiA) * Hi * Wi;
            float v = ((unsigned)iy < (unsigned)Hi && (unsigned)ix < (unsigned)Wi)
                      ? (float)src[(size_t)iy * Wi + ix] : 0.f;
            sIn[ci * IH * IWP + py * IWP + px] = (TIN)v;
        }
        // stage weight chunk: [ci][t9][co]
        for (int e = t; e < cn * 144; e += 256) {
            int ci = e / 144, rem = e % 144;
            int t9 = rem / 16, co = rem % 16;
            sW[ci * 144 + t9 * 16 + co] =
                Wt[(size_t)(cog0 + co) * Ci * 9 + (cb + ci) * 9 + t9];
        }
        __syncthreads();
        for (int ci = 0; ci < cn; ++ci) {
            #pragma unroll
            for (int t9 = 0; t9 < 9; ++t9) {
                int ky = t9 / 3, kx = t9 % 3;
                float v = (float)sIn[ci * IH * IWP + (ty * STRIDE + ky) * IWP
                                     + (tx * STRIDE + kx)];
                const float* wp = &sW[ci * 144 + t9 * 16];
                #pragma unroll
                for (int co = 0; co < 16; ++co)
                    acc[co] = fmaf(v, wp[co], acc[co]);
            }
        }
        __syncthreads();
    }

    int oy = ty0 + ty, ox = tx0 + tx;
    #pragma unroll
    for (int co = 0; co < 16; ++co)
        out[(size_t)(n * Co + cog0 + co) * Ho * Wo + (size_t)oy * Wo + ox]
            = f2bf(fmaxf(acc[co], 0.f));
}

// ===========================================================================
// Tiled transposed conv (k=3,s=2,p=1,op=1) as lhs-dilated conv, ReLU.
// Output tile 16x16 needs a 9x9 input patch per channel (tile origin even).
// ===========================================================================
__global__ __launch_bounds__(256)
void convt_tiled(const bf* __restrict__ inA, const bf* __restrict__ inB,
                 int CiA, int Ci,
                 const float* __restrict__ Wt, const float* __restrict__ Bias,
                 bf* __restrict__ out,
                 int N, int Hi, int Wi, int Co, int Ho, int Wo, int tilesX)
{
    constexpr int TS = 16;
    constexpr int IH = 9;
    constexpr int CHUNK = 8;
    __shared__ bf sIn[CHUNK * IH * IH];
    __shared__ float sW[CHUNK * 144];

    int tile = blockIdx.x;
    int tx0 = (tile % tilesX) * TS, ty0 = (tile / tilesX) * TS;
    int n = blockIdx.y;
    int cog0 = blockIdx.z * 16;
    int t = threadIdx.x;
    int tx = t & 15, ty = t >> 4;
    int CiB = Ci - CiA;

    // per-thread valid taps (parity): up to 2 in each dim
    int npy = 0, tpy[2], tky[2];
    #pragma unroll
    for (int ky = 0; ky < 3; ++ky) {
        int d = ty + ky - 1;
        if (!(d & 1)) { tpy[npy] = d >> 1; tky[npy] = ky; ++npy; }
    }
    int npx = 0, tpx[2], tkx[2];
    #pragma unroll
    for (int kx = 0; kx < 3; ++kx) {
        int d = tx + kx - 1;
        if (!(d & 1)) { tpx[npx] = d >> 1; tkx[npx] = kx; ++npx; }
    }

    float acc[16];
    #pragma unroll
    for (int c = 0; c < 16; ++c) acc[c] = Bias[cog0 + c];

    for (int cb = 0; cb < Ci; cb += CHUNK) {
        int cn = (Ci - cb < CHUNK) ? (Ci - cb) : CHUNK;
        for (int e = t; e < cn * IH * IH; e += 256) {
            int ci = e / (IH * IH);
            int rem = e % (IH * IH);
            int py = rem / IH, px = rem % IH;
            int iy = (ty0 >> 1) + py;
            int ix = (tx0 >> 1) + px;
            int gci = cb + ci;
            const bf* src = (gci < CiA)
                ? inA + (size_t)(n * CiA + gci) * Hi * Wi
                : inB + (size_t)(n * CiB + gci - CiA) * Hi * Wi;
            float v = ((unsigned)iy < (unsigned)Hi && (unsigned)ix < (unsigned)Wi)
                      ? bf2f(src[(size_t)iy * Wi + ix]) : 0.f;
            sIn[ci * IH * IH + py * IH + px] = f2bf(v);
        }
        for (int e = t; e < cn * 144; e += 256) {
            int ci = e / 144, rem = e % 144;
            int t9 = rem / 16, co = rem % 16;
            sW[ci * 144 + t9 * 16 + co] =
                Wt[(size_t)(cog0 + co) * Ci * 9 + (cb + ci) * 9 + t9];
        }
        __syncthreads();
        for (int ci = 0; ci < cn; ++ci) {
            for (int a = 0; a < npy; ++a)
                for (int b = 0; b < npx; ++b) {
                    float v = bf2f(sIn[ci * IH * IH + tpy[a] * IH + tpx[b]]);
                    const float* wp = &sW[ci * 144 + (tky[a] * 3 + tkx[b]) * 16];
                    #pragma unroll
                    for (int co = 0; co < 16; ++co)
                        acc[co] = fmaf(v, wp[co], acc[co]);
                }
        }
        __syncthreads();
    }

    int oy = ty0 + ty, ox = tx0 + tx;
    #pragma unroll
    for (int co = 0; co < 16; ++co)
        out[(size_t)(n * Co + cog0 + co) * Ho * Wo + (size_t)oy * Wo + ox]
            = f2bf(fmaxf(acc[co], 0.f));
}

// ===========================================================================
// Pairwise Gram partials over 256-feature chunks. Deterministic.
// ===========================================================================
#define SCH 256
__global__ void sim_partial(const bf* __restrict__ f, float* __restrict__ part, int KTOT)
{
    __shared__ float tile[32][SCH + 1];
    int c = blockIdx.x;
    int t = threadIdx.x;
    int k0 = c * SCH;
    for (int r = 0; r < 32; ++r)
        tile[r][t] = bf2f(f[(size_t)r * KTOT + k0 + t]);
    __syncthreads();
    int i = t >> 3;
    int j0 = (t & 7) * 4;
    float a0 = 0.f, a1 = 0.f, a2 = 0.f, a3 = 0.f;
    for (int k = 0; k < SCH; ++k) {
        float fi = tile[i][k];
        a0 = fmaf(fi, tile[j0 + 0][k], a0);
        a1 = fmaf(fi, tile[j0 + 1][k], a1);
        a2 = fmaf(fi, tile[j0 + 2][k], a2);
        a3 = fmaf(fi, tile[j0 + 3][k], a3);
    }
    float* dst = part + (size_t)c * 1024 + i * 32 + j0;
    dst[0] = a0; dst[1] = a1; dst[2] = a2; dst[3] = a3;
}

__global__ void sim_reduce(const float* __restrict__ part, float* __restrict__ sim,
                           int nchunks, int total)
{
    int t = blockIdx.x * blockDim.x + threadIdx.x;
    if (t >= total) return;
    float s = 0.f;
    for (int c = 0; c < nchunks; ++c) s += part[(size_t)c * 1024 + t];
    sim[t] = s;
}

// ===========================================================================
// Cosine sim + group mask + top-3 (strict >, lowest index wins ties).
// ===========================================================================
__global__ void topk_kernel(const float* __restrict__ sim, const int* __restrict__ prange,
                            int* __restrict__ idx, int N)
{
    int i = threadIdx.x;
    if (i >= N) return;
    float nm_i = fmaxf(sqrtf(sim[i * N + i]), 1e-8f);
    int p0 = prange[0], p1 = prange[1];
    int gi = (i >= p0) + (i >= p1);
    float vals[32];
    for (int j = 0; j < N; ++j) {
        int gj = (j >= p0) + (j >= p1);
        if (j == i || gj != gi) { vals[j] = -1e30f; continue; }
        float nm_j = fmaxf(sqrtf(sim[j * N + j]), 1e-8f);
        vals[j] = sim[i * N + j] / (nm_i * nm_j);
    }
    for (int k = 0; k < 3; ++k) {
        float best = -2e30f; int bj = 0;
        for (int j = 0; j < N; ++j)
            if (vals[j] > best) { best = vals[j]; bj = j; }
        idx[i * 3 + k] = bj;
        vals[bj] = -1e30f;
    }
}

// ===========================================================================
// Tiled KNN aggregation: agg = mean_k relu(conv3x3(u3[idx[k]], w_ga)).
// Ci=Co=16. Weights fully staged once; input staged per neighbor in 2 chunks.
// ===========================================================================
__global__ __launch_bounds__(256)
void knn_tiled(const bf* __restrict__ u3, const int* __restrict__ idx,
               const float* __restrict__ Wg, const float* __restrict__ Bg,
               bf* __restrict__ agg, int N, int tilesX)
{
    constexpr int IH = 18, IWP = 19, CHUNK = 8;
    __shared__ bf sIn[CHUNK * IH * IWP];
    __shared__ float sW[16 * 144];                 // [ci][t9][co]

    int tile = blockIdx.x;
    int tx0 = (tile % tilesX) * 16, ty0 = (tile / tilesX) * 16;
    int n = blockIdx.y;
    int t = threadIdx.x;
    int tx = t & 15, ty = t >> 4;

    for (int e = t; e < 16 * 144; e += 256) {
        int ci = e / 144, rem = e % 144;
        int t9 = rem / 16, co = rem % 16;
        sW[ci * 144 + t9 * 16 + co] = Wg[(co * 16 + ci) * 9 + t9];
    }

    float sum[16];
    #pragma unroll
    for (int c = 0; c < 16; ++c) sum[c] = 0.f;

    for (int k = 0; k < 3; ++k) {
        int nb = idx[n * 3 + k];
        float acc[16];
        #pragma unroll
        for (int c = 0; c < 16; ++c) acc[c] = Bg[c];
        for (int cb = 0; cb < 16; cb += CHUNK) {
            __syncthreads();
            for (int e = t; e < CHUNK * IH * IH; e += 256) {
                int ci = e / (IH * IH);
                int rem = e % (IH * IH);
                int py = rem / IH, px = rem % IH;
                int iy = ty0 - 1 + py, ix = tx0 - 1 + px;
                const bf* src = u3 + ((size_t)(nb * 16 + cb + ci) << 16);
                float v = ((unsigned)iy < 256u && (unsigned)ix < 256u)
                          ? bf2f(src[(iy << 8) + ix]) : 0.f;
                sIn[ci * IH * IWP + py * IWP + px] = f2bf(v);
            }
            __syncthreads();
            for (int ci = 0; ci < CHUNK; ++ci) {
                #pragma unroll
                for (int t9 = 0; t9 < 9; ++t9) {
                    int ky = t9 / 3, kx = t9 % 3;
                    float v = bf2f(sIn[ci * IH * IWP + (ty + ky) * IWP + tx + kx]);
                    const float* wp = &sW[(cb + ci) * 144 + t9 * 16];
                    #pragma unroll
                    for (int co = 0; co < 16; ++co)
                        acc[co] = fmaf(v, wp[co], acc[co]);
                }
            }
        }
        #pragma unroll
        for (int c = 0; c < 16; ++c) sum[c] += fmaxf(acc[c], 0.f);
    }

    int oy = ty0 + ty, ox = tx0 + tx;
    #pragma unroll
    for (int co = 0; co < 16; ++co)
        agg[((size_t)(n * 16 + co) << 16) + (oy << 8) + ox]
            = f2bf(sum[co] * (1.f / 3.f));
}

// ===========================================================================
// Tiled fused epilogue: gnn conv (32->16) + d1 recompute + dense 32->2 +
// softmax. f32 NCHW store.
// ===========================================================================
__global__ __launch_bounds__(256)
void final_tiled(const float* __restrict__ cts, const bf* __restrict__ u3,
                 const bf* __restrict__ agg,
                 const float* __restrict__ w_d1, const float* __restrict__ b_d1,
                 const float* __restrict__ w_gu, const float* __restrict__ b_gu,
                 const float* __restrict__ w_de, const float* __restrict__ b_de,
                 float* __restrict__ out, int N, int tilesX)
{
    constexpr int IH = 18, IWP = 19, CHUNK = 8;
    __shared__ bf sIn[CHUNK * IH * IWP];
    __shared__ float sW[32 * 144];                 // [ci][t9][co]
    __shared__ float sDe[64];

    int tile = blockIdx.x;
    int tx0 = (tile % tilesX) * 16, ty0 = (tile / tilesX) * 16;
    int n = blockIdx.y;
    int t = threadIdx.x;
    int tx = t & 15, ty = t >> 4;

    for (int e = t; e < 32 * 144; e += 256) {
        int ci = e / 144, rem = e % 144;
        int t9 = rem / 16, co = rem % 16;
        sW[ci * 144 + t9 * 16 + co] = w_gu[(size_t)(co * 32 + ci) * 9 + t9];
    }
    if (t < 64) sDe[t] = w_de[t];

    float g[16];
    #pragma unroll
    for (int c = 0; c < 16; ++c) g[c] = b_gu[c];

    for (int cb = 0; cb < 32; cb += CHUNK) {
        __syncthreads();
        for (int e = t; e < CHUNK * IH * IH; e += 256) {
            int ci = e / (IH * IH);
            int rem = e % (IH * IH);
            int py = rem / IH, px = rem % IH;
            int iy = ty0 - 1 + py, ix = tx0 - 1 + px;
            int gci = cb + ci;
            const bf* src = (gci < 16) ? u3 + ((size_t)(n * 16 + gci) << 16)
                                       : agg + ((size_t)(n * 16 + gci - 16) << 16);
            float v = ((unsigned)iy < 256u && (unsigned)ix < 256u)
                      ? bf2f(src[(iy << 8) + ix]) : 0.f;
            sIn[ci * IH * IWP + py * IWP + px] = f2bf(v);
        }
        __syncthreads();
        for (int ci = 0; ci < CHUNK; ++ci) {
            #pragma unroll
            for (int t9 = 0; t9 < 9; ++t9) {
                int ky = t9 / 3, kx = t9 % 3;
                float v = bf2f(sIn[ci * IH * IWP + (ty + ky) * IWP + tx + kx]);
                const float* wp = &sW[(cb + ci) * 144 + t9 * 16];
                #pragma unroll
                for (int co = 0; co < 16; ++co)
                    g[co] = fmaf(v, wp[co], g[co]);
            }
        }
    }

    float l0 = b_de[0], l1 = b_de[1];
    #pragma unroll
    for (int c = 0; c < 16; ++c) {
        float v = fmaxf(g[c], 0.f);
        l0 = fmaf(v, sDe[c * 2 + 0], l0);
        l1 = fmaf(v, sDe[c * 2 + 1], l1);
    }

    // d1 recompute from f32 cts (1 input channel)
    int y = ty0 + ty, x = tx0 + tx;
    const float* csrc = cts + ((size_t)n << 16);
    float ct[9];
    #pragma unroll
    for (int ky = 0; ky < 3; ++ky) {
        int iy = y + ky - 1;
        #pragma unroll
        for (int kx = 0; kx < 3; ++kx) {
            int ix = x + kx - 1;
            ct[ky * 3 + kx] = ((unsigned)iy < 256u && (unsigned)ix < 256u)
                              ? csrc[(iy << 8) + ix] : 0.f;
        }
    }
    #pragma unroll
    for (int c = 0; c < 16; ++c) {
        float acc = b_d1[c];
        const float* wp = w_d1 + c * 9;
        #pragma unroll
        for (int t9 = 0; t9 < 9; ++t9) acc = fmaf(ct[t9], wp[t9], acc);
        float v = fmaxf(acc, 0.f);
        l0 = fmaf(v, sDe[(16 + c) * 2 + 0], l0);
        l1 = fmaf(v, sDe[(16 + c) * 2 + 1], l1);
    }

    float m = fmaxf(l0, l1);
    float e0 = expf(l0 - m), e1 = expf(l1 - m);
    float inv = 1.f / (e0 + e1);
    size_t base = ((size_t)n * 2) << 16;
    out[base + (y << 8) + x] = e0 * inv;
    out[base + (1 << 16) + (y << 8) + x] = e1 * inv;
}

// ===========================================================================

extern "C" void kernel_launch(void* const* d_in, const int* in_sizes, int n_in,
                              void* d_out, int out_size, void* d_ws, size_t ws_size,
                              hipStream_t stream)
{
    const float* cts  = (const float*)d_in[0];
    const int*   prng = (const int*)d_in[1];
    const float* w_d1 = (const float*)d_in[2];  const float* b_d1 = (const float*)d_in[3];
    const float* w_d2 = (const float*)d_in[4];  const float* b_d2 = (const float*)d_in[5];
    const float* w_d3 = (const float*)d_in[6];  const float* b_d3 = (const float*)d_in[7];
    const float* w_d4 = (const float*)d_in[8];  const float* b_d4 = (const float*)d_in[9];
    const float* w_u1 = (const float*)d_in[10]; const float* b_u1 = (const float*)d_in[11];
    const float* w_u2 = (const float*)d_in[12]; const float* b_u2 = (const float*)d_in[13];
    const float* w_u3 = (const float*)d_in[14]; const float* b_u3 = (const float*)d_in[15];
    const float* w_ga = (const float*)d_in[16]; const float* b_ga = (const float*)d_in[17];
    const float* w_gu = (const float*)d_in[18]; const float* b_gu = (const float*)d_in[19];
    const float* w_de = (const float*)d_in[20]; const float* b_de = (const float*)d_in[21];

    const int H = 256, Wd = 256;
    const int N = in_sizes[0] / (H * Wd);   // 32

    // ---- workspace layout (bytes), bf16 feature maps, lifetime reuse ----
    // U3  [64 MiB] : u3 (persists)
    // AGG [64 MiB] : d1 -> u1 [0:16M] + u2 [16M:48M] -> agg
    // T1  [32 MiB] : d2 -> simp(16.7M f32)
    // T2  [32 MiB] : d3 [0:16M] + d4 [16M:24M] -> idx; sim at +16M
    char* wsb = (char*)d_ws;
    bf* U3  = (bf*)(wsb);
    bf* AGG = (bf*)(wsb + 67108864);
    bf* T1  = (bf*)(wsb + 134217728);
    bf* T2  = (bf*)(wsb + 167772160);

    bf* d1 = AGG;
    bf* d2 = T1;
    bf* d3 = T2;
    bf* d4 = (bf*)(wsb + 167772160 + 16777216);
    bf* u1 = AGG;
    bf* u2 = (bf*)(wsb + 67108864 + 16777216);
    bf* u3 = U3;
    float* simp = (float*)T1;
    float* sim  = (float*)(wsb + 134217728 + 16777216);
    int*   idx  = (int*)T2;
    bf* agg = AGG;

    const int KTOT = 16 * H * Wd;             // 1,048,576
    const int NCH  = KTOT / SCH;              // 4096

    // encoder
    conv_tiled<float, 1><<<dim3(256, N, 1), 256, 0, stream>>>(
        cts, (const float*)nullptr, 1, 1, w_d1, b_d1, d1, N, 256, 256, 16, 256, 256, 16);
    conv_tiled<bf, 2><<<dim3(64, N, 2), 256, 0, stream>>>(
        d1, (const bf*)nullptr, 16, 16, w_d2, b_d2, d2, N, 256, 256, 32, 128, 128, 8);
    conv_tiled<bf, 2><<<dim3(16, N, 4), 256, 0, stream>>>(
        d2, (const bf*)nullptr, 32, 32, w_d3, b_d3, d3, N, 128, 128, 64, 64, 64, 4);
    conv_tiled<bf, 2><<<dim3(4, N, 8), 256, 0, stream>>>(
        d3, (const bf*)nullptr, 64, 64, w_d4, b_d4, d4, N, 64, 64, 128, 32, 32, 2);
    // decoder
    convt_tiled<<<dim3(16, N, 4), 256, 0, stream>>>(
        d4, (const bf*)nullptr, 128, 128, w_u1, b_u1, u1, N, 32, 32, 64, 64, 64, 4);
    convt_tiled<<<dim3(64, N, 2), 256, 0, stream>>>(
        u1, d3, 64, 128, w_u2, b_u2, u2, N, 64, 64, 32, 128, 128, 8);
    convt_tiled<<<dim3(256, N, 1), 256, 0, stream>>>(
        u2, d2, 32, 64, w_u3, b_u3, u3, N, 128, 128, 16, 256, 256, 16);
    // cosine similarity + top-3
    sim_partial<<<NCH, 256, 0, stream>>>(u3, simp, KTOT);
    sim_reduce<<<(N * N + 255) / 256, 256, 0, stream>>>(simp, sim, NCH, N * N);
    topk_kernel<<<1, 64, 0, stream>>>(sim, prng, idx, N);
    // knn conv + mean
    knn_tiled<<<dim3(256, N), 256, 0, stream>>>(u3, idx, w_ga, b_ga, agg, N, 16);
    // fused gnn conv + d1 recompute + dense + softmax
    final_tiled<<<dim3(256, N), 256, 0, stream>>>(
        cts, u3, agg, w_d1, b_d1, w_gu, b_gu, w_de, b_de, (float*)d_out, N, 16);
}

// Round 4
// 2638.830 us; speedup vs baseline: 6.9145x; 1.3853x over previous
//
#include <hip/hip_runtime.h>
#include <hip/hip_bf16.h>
#include <math.h>

typedef __hip_bfloat16 bf;

__device__ __forceinline__ float bf2f(bf v) { return __bfloat162float(v); }
__device__ __forceinline__ bf f2bf(float v) { return __float2bfloat16(v); }

// ===========================================================================
// Tiled direct 3x3 conv, pad 1, stride STRIDE, ReLU.
// Block = 256 threads = 16x16 output tile. blockIdx.x = tile, .y = n,
// .z = output-channel group of 16. Input staged in LDS in chunks of 8 ch.
// ===========================================================================
template <typename TIN, int STRIDE>
__global__ __launch_bounds__(256)
void conv_tiled(const TIN* __restrict__ inA, const TIN* __restrict__ inB,
                int CiA, int Ci,
                const float* __restrict__ Wt, const float* __restrict__ Bias,
                bf* __restrict__ out,
                int N, int Hi, int Wi, int Co, int Ho, int Wo, int tilesX)
{
    constexpr int TS = 16;
    constexpr int IH = (TS - 1) * STRIDE + 3;          // 18 or 33
    constexpr int IWP = (IH % 2 == 0) ? IH + 1 : IH;   // 19 or 33
    constexpr int CHUNK = 8;

    __shared__ TIN  sIn[CHUNK * IH * IWP];
    __shared__ float sW[CHUNK * 144];                  // [ci][t9][co16]

    int tile = blockIdx.x;
    int tx0 = (tile % tilesX) * TS, ty0 = (tile / tilesX) * TS;
    int n = blockIdx.y;
    int cog0 = blockIdx.z * 16;
    int t = threadIdx.x;
    int tx = t & 15, ty = t >> 4;
    int CiB = Ci - CiA;

    float acc[16];
    #pragma unroll
    for (int c = 0; c < 16; ++c) acc[c] = Bias[cog0 + c];

    for (int cb = 0; cb < Ci; cb += CHUNK) {
        int cn = (Ci - cb < CHUNK) ? (Ci - cb) : CHUNK;
        for (int e = t; e < cn * IH * IH; e += 256) {
            int ci = e / (IH * IH);
            int rem = e % (IH * IH);
            int py = rem / IH, px = rem % IH;
            int iy = ty0 * STRIDE - 1 + py;
            int ix = tx0 * STRIDE - 1 + px;
            int gci = cb + ci;
            const TIN* src = (gci < CiA)
                ? inA + (size_t)(n * CiA + gci) * Hi * Wi
                : inB + (size_t)(n * CiB + gci - CiA) * Hi * Wi;
            float v = ((unsigned)iy < (unsigned)Hi && (unsigned)ix < (unsigned)Wi)
                      ? (float)src[(size_t)iy * Wi + ix] : 0.f;
            sIn[ci * IH * IWP + py * IWP + px] = (TIN)v;
        }
        for (int e = t; e < cn * 144; e += 256) {
            int ci = e / 144, rem = e % 144;
            int t9 = rem / 16, co = rem % 16;
            sW[ci * 144 + t9 * 16 + co] =
                Wt[(size_t)(cog0 + co) * Ci * 9 + (cb + ci) * 9 + t9];
        }
        __syncthreads();
        for (int ci = 0; ci < cn; ++ci) {
            #pragma unroll
            for (int t9 = 0; t9 < 9; ++t9) {
                int ky = t9 / 3, kx = t9 % 3;
                float v = (float)sIn[ci * IH * IWP + (ty * STRIDE + ky) * IWP
                                     + (tx * STRIDE + kx)];
                const float* wp = &sW[ci * 144 + t9 * 16];
                #pragma unroll
                for (int co = 0; co < 16; ++co)
                    acc[co] = fmaf(v, wp[co], acc[co]);
            }
        }
        __syncthreads();
    }

    int oy = ty0 + ty, ox = tx0 + tx;
    #pragma unroll
    for (int co = 0; co < 16; ++co)
        out[(size_t)(n * Co + cog0 + co) * Ho * Wo + (size_t)oy * Wo + ox]
            = f2bf(fmaxf(acc[co], 0.f));
}

// ===========================================================================
// Tiled transposed conv (k=3,s=2,p=1,op=1) as lhs-dilated conv, ReLU.
// ===========================================================================
__global__ __launch_bounds__(256)
void convt_tiled(const bf* __restrict__ inA, const bf* __restrict__ inB,
                 int CiA, int Ci,
                 const float* __restrict__ Wt, const float* __restrict__ Bias,
                 bf* __restrict__ out,
                 int N, int Hi, int Wi, int Co, int Ho, int Wo, int tilesX)
{
    constexpr int TS = 16;
    constexpr int IH = 9;
    constexpr int CHUNK = 8;
    __shared__ bf sIn[CHUNK * IH * IH];
    __shared__ float sW[CHUNK * 144];

    int tile = blockIdx.x;
    int tx0 = (tile % tilesX) * TS, ty0 = (tile / tilesX) * TS;
    int n = blockIdx.y;
    int cog0 = blockIdx.z * 16;
    int t = threadIdx.x;
    int tx = t & 15, ty = t >> 4;
    int CiB = Ci - CiA;

    int npy = 0, tpy[2], tky[2];
    #pragma unroll
    for (int ky = 0; ky < 3; ++ky) {
        int d = ty + ky - 1;
        if (!(d & 1)) { tpy[npy] = d >> 1; tky[npy] = ky; ++npy; }
    }
    int npx = 0, tpx[2], tkx[2];
    #pragma unroll
    for (int kx = 0; kx < 3; ++kx) {
        int d = tx + kx - 1;
        if (!(d & 1)) { tpx[npx] = d >> 1; tkx[npx] = kx; ++npx; }
    }

    float acc[16];
    #pragma unroll
    for (int c = 0; c < 16; ++c) acc[c] = Bias[cog0 + c];

    for (int cb = 0; cb < Ci; cb += CHUNK) {
        int cn = (Ci - cb < CHUNK) ? (Ci - cb) : CHUNK;
        for (int e = t; e < cn * IH * IH; e += 256) {
            int ci = e / (IH * IH);
            int rem = e % (IH * IH);
            int py = rem / IH, px = rem % IH;
            int iy = (ty0 >> 1) + py;
            int ix = (tx0 >> 1) + px;
            int gci = cb + ci;
            const bf* src = (gci < CiA)
                ? inA + (size_t)(n * CiA + gci) * Hi * Wi
                : inB + (size_t)(n * CiB + gci - CiA) * Hi * Wi;
            float v = ((unsigned)iy < (unsigned)Hi && (unsigned)ix < (unsigned)Wi)
                      ? bf2f(src[(size_t)iy * Wi + ix]) : 0.f;
            sIn[ci * IH * IH + py * IH + px] = f2bf(v);
        }
        for (int e = t; e < cn * 144; e += 256) {
            int ci = e / 144, rem = e % 144;
            int t9 = rem / 16, co = rem % 16;
            sW[ci * 144 + t9 * 16 + co] =
                Wt[(size_t)(cog0 + co) * Ci * 9 + (cb + ci) * 9 + t9];
        }
        __syncthreads();
        for (int ci = 0; ci < cn; ++ci) {
            for (int a = 0; a < npy; ++a)
                for (int b = 0; b < npx; ++b) {
                    float v = bf2f(sIn[ci * IH * IH + tpy[a] * IH + tpx[b]]);
                    const float* wp = &sW[ci * 144 + (tky[a] * 3 + tkx[b]) * 16];
                    #pragma unroll
                    for (int co = 0; co < 16; ++co)
                        acc[co] = fmaf(v, wp[co], acc[co]);
                }
        }
        __syncthreads();
    }

    int oy = ty0 + ty, ox = tx0 + tx;
    #pragma unroll
    for (int co = 0; co < 16; ++co)
        out[(size_t)(n * Co + cog0 + co) * Ho * Wo + (size_t)oy * Wo + ox]
            = f2bf(fmaxf(acc[co], 0.f));
}

// ===========================================================================
// Pairwise Gram partials over 256-feature chunks. Deterministic.
// ===========================================================================
#define SCH 256
__global__ void sim_partial(const bf* __restrict__ f, float* __restrict__ part, int KTOT)
{
    __shared__ float tile[32][SCH + 1];
    int c = blockIdx.x;
    int t = threadIdx.x;
    int k0 = c * SCH;
    for (int r = 0; r < 32; ++r)
        tile[r][t] = bf2f(f[(size_t)r * KTOT + k0 + t]);
    __syncthreads();
    int i = t >> 3;
    int j0 = (t & 7) * 4;
    float a0 = 0.f, a1 = 0.f, a2 = 0.f, a3 = 0.f;
    for (int k = 0; k < SCH; ++k) {
        float fi = tile[i][k];
        a0 = fmaf(fi, tile[j0 + 0][k], a0);
        a1 = fmaf(fi, tile[j0 + 1][k], a1);
        a2 = fmaf(fi, tile[j0 + 2][k], a2);
        a3 = fmaf(fi, tile[j0 + 3][k], a3);
    }
    float* dst = part + (size_t)c * 1024 + i * 32 + j0;
    dst[0] = a0; dst[1] = a1; dst[2] = a2; dst[3] = a3;
}

// One block per (i,j) pair; 256 threads stride the 4096 chunks, LDS tree.
// Fixed order -> deterministic.
__global__ __launch_bounds__(256)
void sim_reduce(const float* __restrict__ part, float* __restrict__ sim, int nchunks)
{
    __shared__ float red[256];
    int pair = blockIdx.x;
    int t = threadIdx.x;
    float s = 0.f;
    for (int k = t; k < nchunks; k += 256)
        s += part[(size_t)k * 1024 + pair];
    red[t] = s;
    __syncthreads();
    #pragma unroll
    for (int off = 128; off > 0; off >>= 1) {
        if (t < off) red[t] += red[t + off];
        __syncthreads();
    }
    if (t == 0) sim[pair] = red[0];
}

// ===========================================================================
// Cosine sim + group mask + top-3 (strict >, lowest index wins ties).
// ===========================================================================
__global__ void topk_kernel(const float* __restrict__ sim, const int* __restrict__ prange,
                            int* __restrict__ idx, int N)
{
    int i = threadIdx.x;
    if (i >= N) return;
    float nm_i = fmaxf(sqrtf(sim[i * N + i]), 1e-8f);
    int p0 = prange[0], p1 = prange[1];
    int gi = (i >= p0) + (i >= p1);
    float vals[32];
    for (int j = 0; j < N; ++j) {
        int gj = (j >= p0) + (j >= p1);
        if (j == i || gj != gi) { vals[j] = -1e30f; continue; }
        float nm_j = fmaxf(sqrtf(sim[j * N + j]), 1e-8f);
        vals[j] = sim[i * N + j] / (nm_i * nm_j);
    }
    for (int k = 0; k < 3; ++k) {
        float best = -2e30f; int bj = 0;
        for (int j = 0; j < N; ++j)
            if (vals[j] > best) { best = vals[j]; bj = j; }
        idx[i * 3 + k] = bj;
        vals[bj] = -1e30f;
    }
}

// ===========================================================================
// Tiled KNN aggregation: agg = mean_k relu(conv3x3(u3[idx[k]], w_ga)).
// ===========================================================================
__global__ __launch_bounds__(256)
void knn_tiled(const bf* __restrict__ u3, const int* __restrict__ idx,
               const float* __restrict__ Wg, const float* __restrict__ Bg,
               bf* __restrict__ agg, int N, int tilesX)
{
    constexpr int IH = 18, IWP = 19, CHUNK = 8;
    __shared__ bf sIn[CHUNK * IH * IWP];
    __shared__ float sW[16 * 144];                 // [ci][t9][co]

    int tile = blockIdx.x;
    int tx0 = (tile % tilesX) * 16, ty0 = (tile / tilesX) * 16;
    int n = blockIdx.y;
    int t = threadIdx.x;
    int tx = t & 15, ty = t >> 4;

    for (int e = t; e < 16 * 144; e += 256) {
        int ci = e / 144, rem = e % 144;
        int t9 = rem / 16, co = rem % 16;
        sW[ci * 144 + t9 * 16 + co] = Wg[(co * 16 + ci) * 9 + t9];
    }

    float sum[16];
    #pragma unroll
    for (int c = 0; c < 16; ++c) sum[c] = 0.f;

    for (int k = 0; k < 3; ++k) {
        int nb = idx[n * 3 + k];
        float acc[16];
        #pragma unroll
        for (int c = 0; c < 16; ++c) acc[c] = Bg[c];
        for (int cb = 0; cb < 16; cb += CHUNK) {
            __syncthreads();
            for (int e = t; e < CHUNK * IH * IH; e += 256) {
                int ci = e / (IH * IH);
                int rem = e % (IH * IH);
                int py = rem / IH, px = rem % IH;
                int iy = ty0 - 1 + py, ix = tx0 - 1 + px;
                const bf* src = u3 + ((size_t)(nb * 16 + cb + ci) << 16);
                float v = ((unsigned)iy < 256u && (unsigned)ix < 256u)
                          ? bf2f(src[(iy << 8) + ix]) : 0.f;
                sIn[ci * IH * IWP + py * IWP + px] = f2bf(v);
            }
            __syncthreads();
            for (int ci = 0; ci < CHUNK; ++ci) {
                #pragma unroll
                for (int t9 = 0; t9 < 9; ++t9) {
                    int ky = t9 / 3, kx = t9 % 3;
                    float v = bf2f(sIn[ci * IH * IWP + (ty + ky) * IWP + tx + kx]);
                    const float* wp = &sW[(cb + ci) * 144 + t9 * 16];
                    #pragma unroll
                    for (int co = 0; co < 16; ++co)
                        acc[co] = fmaf(v, wp[co], acc[co]);
                }
            }
        }
        #pragma unroll
        for (int c = 0; c < 16; ++c) sum[c] += fmaxf(acc[c], 0.f);
    }

    int oy = ty0 + ty, ox = tx0 + tx;
    #pragma unroll
    for (int co = 0; co < 16; ++co)
        agg[((size_t)(n * 16 + co) << 16) + (oy << 8) + ox]
            = f2bf(sum[co] * (1.f / 3.f));
}

// ===========================================================================
// Tiled fused epilogue: gnn conv (32->16) + d1 recompute + dense 32->2 +
// softmax. f32 NCHW store.
// ===========================================================================
__global__ __launch_bounds__(256)
void final_tiled(const float* __restrict__ cts, const bf* __restrict__ u3,
                 const bf* __restrict__ agg,
                 const float* __restrict__ w_d1, const float* __restrict__ b_d1,
                 const float* __restrict__ w_gu, const float* __restrict__ b_gu,
                 const float* __restrict__ w_de, const float* __restrict__ b_de,
                 float* __restrict__ out, int N, int tilesX)
{
    constexpr int IH = 18, IWP = 19, CHUNK = 8;
    __shared__ bf sIn[CHUNK * IH * IWP];
    __shared__ float sW[32 * 144];
    __shared__ float sDe[64];

    int tile = blockIdx.x;
    int tx0 = (tile % tilesX) * 16, ty0 = (tile / tilesX) * 16;
    int n = blockIdx.y;
    int t = threadIdx.x;
    int tx = t & 15, ty = t >> 4;

    for (int e = t; e < 32 * 144; e += 256) {
        int ci = e / 144, rem = e % 144;
        int t9 = rem / 16, co = rem % 16;
        sW[ci * 144 + t9 * 16 + co] = w_gu[(size_t)(co * 32 + ci) * 9 + t9];
    }
    if (t < 64) sDe[t] = w_de[t];

    float g[16];
    #pragma unroll
    for (int c = 0; c < 16; ++c) g[c] = b_gu[c];

    for (int cb = 0; cb < 32; cb += CHUNK) {
        __syncthreads();
        for (int e = t; e < CHUNK * IH * IH; e += 256) {
            int ci = e / (IH * IH);
            int rem = e % (IH * IH);
            int py = rem / IH, px = rem % IH;
            int iy = ty0 - 1 + py, ix = tx0 - 1 + px;
            int gci = cb + ci;
            const bf* src = (gci < 16) ? u3 + ((size_t)(n * 16 + gci) << 16)
                                       : agg + ((size_t)(n * 16 + gci - 16) << 16);
            float v = ((unsigned)iy < 256u && (unsigned)ix < 256u)
                      ? bf2f(src[(iy << 8) + ix]) : 0.f;
            sIn[ci * IH * IWP + py * IWP + px] = f2bf(v);
        }
        __syncthreads();
        for (int ci = 0; ci < CHUNK; ++ci) {
            #pragma unroll
            for (int t9 = 0; t9 < 9; ++t9) {
                int ky = t9 / 3, kx = t9 % 3;
                float v = bf2f(sIn[ci * IH * IWP + (ty + ky) * IWP + tx + kx]);
                const float* wp = &sW[(cb + ci) * 144 + t9 * 16];
                #pragma unroll
                for (int co = 0; co < 16; ++co)
                    g[co] = fmaf(v, wp[co], g[co]);
            }
        }
    }

    float l0 = b_de[0], l1 = b_de[1];
    #pragma unroll
    for (int c = 0; c < 16; ++c) {
        float v = fmaxf(g[c], 0.f);
        l0 = fmaf(v, sDe[c * 2 + 0], l0);
        l1 = fmaf(v, sDe[c * 2 + 1], l1);
    }

    int y = ty0 + ty, x = tx0 + tx;
    const float* csrc = cts + ((size_t)n << 16);
    float ct[9];
    #pragma unroll
    for (int ky = 0; ky < 3; ++ky) {
        int iy = y + ky - 1;
        #pragma unroll
        for (int kx = 0; kx < 3; ++kx) {
            int ix = x + kx - 1;
            ct[ky * 3 + kx] = ((unsigned)iy < 256u && (unsigned)ix < 256u)
                              ? csrc[(iy << 8) + ix] : 0.f;
        }
    }
    #pragma unroll
    for (int c = 0; c < 16; ++c) {
        float acc = b_d1[c];
        const float* wp = w_d1 + c * 9;
        #pragma unroll
        for (int t9 = 0; t9 < 9; ++t9) acc = fmaf(ct[t9], wp[t9], acc);
        float v = fmaxf(acc, 0.f);
        l0 = fmaf(v, sDe[(16 + c) * 2 + 0], l0);
        l1 = fmaf(v, sDe[(16 + c) * 2 + 1], l1);
    }

    float m = fmaxf(l0, l1);
    float e0 = expf(l0 - m), e1 = expf(l1 - m);
    float inv = 1.f / (e0 + e1);
    size_t base = ((size_t)n * 2) << 16;
    out[base + (y << 8) + x] = e0 * inv;
    out[base + (1 << 16) + (y << 8) + x] = e1 * inv;
}

// ===========================================================================

extern "C" void kernel_launch(void* const* d_in, const int* in_sizes, int n_in,
                              void* d_out, int out_size, void* d_ws, size_t ws_size,
                              hipStream_t stream)
{
    const float* cts  = (const float*)d_in[0];
    const int*   prng = (const int*)d_in[1];
    const float* w_d1 = (const float*)d_in[2];  const float* b_d1 = (const float*)d_in[3];
    const float* w_d2 = (const float*)d_in[4];  const float* b_d2 = (const float*)d_in[5];
    const float* w_d3 = (const float*)d_in[6];  const float* b_d3 = (const float*)d_in[7];
    const float* w_d4 = (const float*)d_in[8];  const float* b_d4 = (const float*)d_in[9];
    const float* w_u1 = (const float*)d_in[10]; const float* b_u1 = (const float*)d_in[11];
    const float* w_u2 = (const float*)d_in[12]; const float* b_u2 = (const float*)d_in[13];
    const float* w_u3 = (const float*)d_in[14]; const float* b_u3 = (const float*)d_in[15];
    const float* w_ga = (const float*)d_in[16]; const float* b_ga = (const float*)d_in[17];
    const float* w_gu = (const float*)d_in[18]; const float* b_gu = (const float*)d_in[19];
    const float* w_de = (const float*)d_in[20]; const float* b_de = (const float*)d_in[21];

    const int H = 256, Wd = 256;
    const int N = in_sizes[0] / (H * Wd);   // 32

    // ---- workspace layout (bytes), bf16 feature maps, lifetime reuse ----
    char* wsb = (char*)d_ws;
    bf* U3  = (bf*)(wsb);
    bf* AGG = (bf*)(wsb + 67108864);
    bf* T1  = (bf*)(wsb + 134217728);
    bf* T2  = (bf*)(wsb + 167772160);

    bf* d1 = AGG;
    bf* d2 = T1;
    bf* d3 = T2;
    bf* d4 = (bf*)(wsb + 167772160 + 16777216);
    bf* u1 = AGG;
    bf* u2 = (bf*)(wsb + 67108864 + 16777216);
    bf* u3 = U3;
    float* simp = (float*)T1;
    float* sim  = (float*)(wsb + 134217728 + 16777216);
    int*   idx  = (int*)T2;
    bf* agg = AGG;

    const int KTOT = 16 * H * Wd;             // 1,048,576
    const int NCH  = KTOT / SCH;              // 4096

    // encoder
    conv_tiled<float, 1><<<dim3(256, N, 1), 256, 0, stream>>>(
        cts, (const float*)nullptr, 1, 1, w_d1, b_d1, d1, N, 256, 256, 16, 256, 256, 16);
    conv_tiled<bf, 2><<<dim3(64, N, 2), 256, 0, stream>>>(
        d1, (const bf*)nullptr, 16, 16, w_d2, b_d2, d2, N, 256, 256, 32, 128, 128, 8);
    conv_tiled<bf, 2><<<dim3(16, N, 4), 256, 0, stream>>>(
        d2, (const bf*)nullptr, 32, 32, w_d3, b_d3, d3, N, 128, 128, 64, 64, 64, 4);
    conv_tiled<bf, 2><<<dim3(4, N, 8), 256, 0, stream>>>(
        d3, (const bf*)nullptr, 64, 64, w_d4, b_d4, d4, N, 64, 64, 128, 32, 32, 2);
    // decoder
    convt_tiled<<<dim3(16, N, 4), 256, 0, stream>>>(
        d4, (const bf*)nullptr, 128, 128, w_u1, b_u1, u1, N, 32, 32, 64, 64, 64, 4);
    convt_tiled<<<dim3(64, N, 2), 256, 0, stream>>>(
        u1, d3, 64, 128, w_u2, b_u2, u2, N, 64, 64, 32, 128, 128, 8);
    convt_tiled<<<dim3(256, N, 1), 256, 0, stream>>>(
        u2, d2, 32, 64, w_u3, b_u3, u3, N, 128, 128, 16, 256, 256, 16);
    // cosine similarity + top-3
    sim_partial<<<NCH, 256, 0, stream>>>(u3, simp, KTOT);
    sim_reduce<<<dim3(N * N), 256, 0, stream>>>(simp, sim, NCH);
    topk_kernel<<<1, 64, 0, stream>>>(sim, prng, idx, N);
    // knn conv + mean
    knn_tiled<<<dim3(256, N), 256, 0, stream>>>(u3, idx, w_ga, b_ga, agg, N, 16);
    // fused gnn conv + d1 recompute + dense + softmax
    final_tiled<<<dim3(256, N), 256, 0, stream>>>(
        cts, u3, agg, w_d1, b_d1, w_gu, b_gu, w_de, b_de, (float*)d_out, N, 16);
}

// Round 5
// 2303.385 us; speedup vs baseline: 7.9215x; 1.1456x over previous
//
#include <hip/hip_runtime.h>
#include <hip/hip_bf16.h>
#include <math.h>

typedef __hip_bfloat16 bf;

__device__ __forceinline__ float bf2f(bf v) { return __bfloat162float(v); }
__device__ __forceinline__ bf f2bf(float v) { return __float2bfloat16(v); }

// ===========================================================================
// Tiled direct 3x3 conv, pad 1, stride STRIDE, ReLU.
// Block = 256 threads = 16x16 output tile. blockIdx.x = tile, .y = n,
// .z = output-channel group of 16. Input staged in LDS in chunks of 8 ch.
// ===========================================================================
template <typename TIN, int STRIDE>
__global__ __launch_bounds__(256)
void conv_tiled(const TIN* __restrict__ inA, const TIN* __restrict__ inB,
                int CiA, int Ci,
                const float* __restrict__ Wt, const float* __restrict__ Bias,
                bf* __restrict__ out,
                int N, int Hi, int Wi, int Co, int Ho, int Wo, int tilesX)
{
    constexpr int TS = 16;
    constexpr int IH = (TS - 1) * STRIDE + 3;          // 18 or 33
    constexpr int IWP = (IH % 2 == 0) ? IH + 1 : IH;   // 19 or 33
    constexpr int CHUNK = 8;

    __shared__ TIN  sIn[CHUNK * IH * IWP];
    __shared__ float sW[CHUNK * 144];                  // [ci][t9][co16]

    int tile = blockIdx.x;
    int tx0 = (tile % tilesX) * TS, ty0 = (tile / tilesX) * TS;
    int n = blockIdx.y;
    int cog0 = blockIdx.z * 16;
    int t = threadIdx.x;
    int tx = t & 15, ty = t >> 4;
    int CiB = Ci - CiA;

    float acc[16];
    #pragma unroll
    for (int c = 0; c < 16; ++c) acc[c] = Bias[cog0 + c];

    for (int cb = 0; cb < Ci; cb += CHUNK) {
        int cn = (Ci - cb < CHUNK) ? (Ci - cb) : CHUNK;
        for (int e = t; e < cn * IH * IH; e += 256) {
            int ci = e / (IH * IH);
            int rem = e % (IH * IH);
            int py = rem / IH, px = rem % IH;
            int iy = ty0 * STRIDE - 1 + py;
            int ix = tx0 * STRIDE - 1 + px;
            int gci = cb + ci;
            const TIN* src = (gci < CiA)
                ? inA + (size_t)(n * CiA + gci) * Hi * Wi
                : inB + (size_t)(n * CiB + gci - CiA) * Hi * Wi;
            float v = ((unsigned)iy < (unsigned)Hi && (unsigned)ix < (unsigned)Wi)
                      ? (float)src[(size_t)iy * Wi + ix] : 0.f;
            sIn[ci * IH * IWP + py * IWP + px] = (TIN)v;
        }
        for (int e = t; e < cn * 144; e += 256) {
            int ci = e / 144, rem = e % 144;
            int t9 = rem / 16, co = rem % 16;
            sW[ci * 144 + t9 * 16 + co] =
                Wt[(size_t)(cog0 + co) * Ci * 9 + (cb + ci) * 9 + t9];
        }
        __syncthreads();
        for (int ci = 0; ci < cn; ++ci) {
            #pragma unroll
            for (int t9 = 0; t9 < 9; ++t9) {
                int ky = t9 / 3, kx = t9 % 3;
                float v = (float)sIn[ci * IH * IWP + (ty * STRIDE + ky) * IWP
                                     + (tx * STRIDE + kx)];
                const float* wp = &sW[ci * 144 + t9 * 16];
                #pragma unroll
                for (int co = 0; co < 16; ++co)
                    acc[co] = fmaf(v, wp[co], acc[co]);
            }
        }
        __syncthreads();
    }

    int oy = ty0 + ty, ox = tx0 + tx;
    #pragma unroll
    for (int co = 0; co < 16; ++co)
        out[(size_t)(n * Co + cog0 + co) * Ho * Wo + (size_t)oy * Wo + ox]
            = f2bf(fmaxf(acc[co], 0.f));
}

// ===========================================================================
// Tiled transposed conv (k=3,s=2,p=1,op=1) as lhs-dilated conv, ReLU.
// Input patch staged as f32 with row stride 10 (bank-conflict-free).
// ===========================================================================
__global__ __launch_bounds__(256)
void convt_tiled(const bf* __restrict__ inA, const bf* __restrict__ inB,
                 int CiA, int Ci,
                 const float* __restrict__ Wt, const float* __restrict__ Bias,
                 bf* __restrict__ out,
                 int N, int Hi, int Wi, int Co, int Ho, int Wo, int tilesX)
{
    constexpr int TS = 16;
    constexpr int IH = 9;
    constexpr int IWP = 10;
    constexpr int CHUNK = 8;
    __shared__ float sIn[CHUNK * IH * IWP];
    __shared__ float sW[CHUNK * 144];

    int tile = blockIdx.x;
    int tx0 = (tile % tilesX) * TS, ty0 = (tile / tilesX) * TS;
    int n = blockIdx.y;
    int cog0 = blockIdx.z * 16;
    int t = threadIdx.x;
    int tx = t & 15, ty = t >> 4;
    int CiB = Ci - CiA;

    int npy = 0, tpy[2], tky[2];
    #pragma unroll
    for (int ky = 0; ky < 3; ++ky) {
        int d = ty + ky - 1;
        if (!(d & 1)) { tpy[npy] = d >> 1; tky[npy] = ky; ++npy; }
    }
    int npx = 0, tpx[2], tkx[2];
    #pragma unroll
    for (int kx = 0; kx < 3; ++kx) {
        int d = tx + kx - 1;
        if (!(d & 1)) { tpx[npx] = d >> 1; tkx[npx] = kx; ++npx; }
    }

    float acc[16];
    #pragma unroll
    for (int c = 0; c < 16; ++c) acc[c] = Bias[cog0 + c];

    for (int cb = 0; cb < Ci; cb += CHUNK) {
        int cn = (Ci - cb < CHUNK) ? (Ci - cb) : CHUNK;
        for (int e = t; e < cn * IH * IH; e += 256) {
            int ci = e / (IH * IH);
            int rem = e % (IH * IH);
            int py = rem / IH, px = rem % IH;
            int iy = (ty0 >> 1) + py;
            int ix = (tx0 >> 1) + px;
            int gci = cb + ci;
            const bf* src = (gci < CiA)
                ? inA + (size_t)(n * CiA + gci) * Hi * Wi
                : inB + (size_t)(n * CiB + gci - CiA) * Hi * Wi;
            float v = ((unsigned)iy < (unsigned)Hi && (unsigned)ix < (unsigned)Wi)
                      ? bf2f(src[(size_t)iy * Wi + ix]) : 0.f;
            sIn[ci * IH * IWP + py * IWP + px] = v;
        }
        for (int e = t; e < cn * 144; e += 256) {
            int ci = e / 144, rem = e % 144;
            int t9 = rem / 16, co = rem % 16;
            sW[ci * 144 + t9 * 16 + co] =
                Wt[(size_t)(cog0 + co) * Ci * 9 + (cb + ci) * 9 + t9];
        }
        __syncthreads();
        for (int ci = 0; ci < cn; ++ci) {
            for (int a = 0; a < npy; ++a)
                for (int b = 0; b < npx; ++b) {
                    float v = sIn[ci * IH * IWP + tpy[a] * IWP + tpx[b]];
                    const float* wp = &sW[ci * 144 + (tky[a] * 3 + tkx[b]) * 16];
                    #pragma unroll
                    for (int co = 0; co < 16; ++co)
                        acc[co] = fmaf(v, wp[co], acc[co]);
                }
        }
        __syncthreads();
    }

    int oy = ty0 + ty, ox = tx0 + tx;
    #pragma unroll
    for (int co = 0; co < 16; ++co)
        out[(size_t)(n * Co + cog0 + co) * Ho * Wo + (size_t)oy * Wo + ox]
            = f2bf(fmaxf(acc[co], 0.f));
}

// ===========================================================================
// Pairwise Gram partials over 256-feature chunks. Deterministic.
// ===========================================================================
#define SCH 256
__global__ void sim_partial(const bf* __restrict__ f, float* __restrict__ part, int KTOT)
{
    __shared__ float tile[32][SCH + 1];
    int c = blockIdx.x;
    int t = threadIdx.x;
    int k0 = c * SCH;
    for (int r = 0; r < 32; ++r)
        tile[r][t] = bf2f(f[(size_t)r * KTOT + k0 + t]);
    __syncthreads();
    int i = t >> 3;
    int j0 = (t & 7) * 4;
    float a0 = 0.f, a1 = 0.f, a2 = 0.f, a3 = 0.f;
    for (int k = 0; k < SCH; ++k) {
        float fi = tile[i][k];
        a0 = fmaf(fi, tile[j0 + 0][k], a0);
        a1 = fmaf(fi, tile[j0 + 1][k], a1);
        a2 = fmaf(fi, tile[j0 + 2][k], a2);
        a3 = fmaf(fi, tile[j0 + 3][k], a3);
    }
    float* dst = part + (size_t)c * 1024 + i * 32 + j0;
    dst[0] = a0; dst[1] = a1; dst[2] = a2; dst[3] = a3;
}

// One block per (i,j) pair; 256 threads stride the chunks, LDS tree.
__global__ __launch_bounds__(256)
void sim_reduce(const float* __restrict__ part, float* __restrict__ sim, int nchunks)
{
    __shared__ float red[256];
    int pair = blockIdx.x;
    int t = threadIdx.x;
    float s = 0.f;
    for (int k = t; k < nchunks; k += 256)
        s += part[(size_t)k * 1024 + pair];
    red[t] = s;
    __syncthreads();
    #pragma unroll
    for (int off = 128; off > 0; off >>= 1) {
        if (t < off) red[t] += red[t + off];
        __syncthreads();
    }
    if (t == 0) sim[pair] = red[0];
}

// ===========================================================================
// Cosine sim + group mask + top-3 (strict >, lowest index wins ties).
// ===========================================================================
__global__ void topk_kernel(const float* __restrict__ sim, const int* __restrict__ prange,
                            int* __restrict__ idx, int N)
{
    int i = threadIdx.x;
    if (i >= N) return;
    float nm_i = fmaxf(sqrtf(sim[i * N + i]), 1e-8f);
    int p0 = prange[0], p1 = prange[1];
    int gi = (i >= p0) + (i >= p1);
    float vals[32];
    for (int j = 0; j < N; ++j) {
        int gj = (j >= p0) + (j >= p1);
        if (j == i || gj != gi) { vals[j] = -1e30f; continue; }
        float nm_j = fmaxf(sqrtf(sim[j * N + j]), 1e-8f);
        vals[j] = sim[i * N + j] / (nm_i * nm_j);
    }
    for (int k = 0; k < 3; ++k) {
        float best = -2e30f; int bj = 0;
        for (int j = 0; j < N; ++j)
            if (vals[j] > best) { best = vals[j]; bj = j; }
        idx[i * 3 + k] = bj;
        vals[bj] = -1e30f;
    }
}

// ===========================================================================
// Gather-mean: agg[n] = (ga[i0] + ga[i1] + ga[i2]) / 3, vectorized 8 bf/thread.
// ===========================================================================
__global__ __launch_bounds__(256)
void gather_mean(const bf* __restrict__ ga, const int* __restrict__ idx,
                 bf* __restrict__ agg)
{
    int n = blockIdx.y;
    int v = blockIdx.x * 256 + threadIdx.x;          // vec index, 8 bf each
    int i0 = idx[n * 3 + 0], i1 = idx[n * 3 + 1], i2 = idx[n * 3 + 2];
    const size_t stride = (size_t)16 << 16;          // elems per slice
    const uint4* p0 = (const uint4*)(ga + stride * i0) + v;
    const uint4* p1 = (const uint4*)(ga + stride * i1) + v;
    const uint4* p2 = (const uint4*)(ga + stride * i2) + v;
    uint4 a = *p0, b = *p1, c = *p2;
    uint4 r;
    unsigned* ap = (unsigned*)&a; unsigned* bp = (unsigned*)&b;
    unsigned* cp = (unsigned*)&c; unsigned* rp = (unsigned*)&r;
    #pragma unroll
    for (int w = 0; w < 4; ++w) {
        unsigned lo, hi;
        {
            float fa = __bfloat162float((__hip_bfloat16_raw){(unsigned short)(ap[w] & 0xffff)});
            float fb = __bfloat162float((__hip_bfloat16_raw){(unsigned short)(bp[w] & 0xffff)});
            float fc = __bfloat162float((__hip_bfloat16_raw){(unsigned short)(cp[w] & 0xffff)});
            __hip_bfloat16 o = __float2bfloat16((fa + fb + fc) * (1.f / 3.f));
            lo = ((__hip_bfloat16_raw)o).x;
        }
        {
            float fa = __bfloat162float((__hip_bfloat16_raw){(unsigned short)(ap[w] >> 16)});
            float fb = __bfloat162float((__hip_bfloat16_raw){(unsigned short)(bp[w] >> 16)});
            float fc = __bfloat162float((__hip_bfloat16_raw){(unsigned short)(cp[w] >> 16)});
            __hip_bfloat16 o = __float2bfloat16((fa + fb + fc) * (1.f / 3.f));
            hi = ((__hip_bfloat16_raw)o).x;
        }
        rp[w] = lo | (hi << 16);
    }
    *((uint4*)(agg + stride * n) + v) = r;
}

// ===========================================================================
// Tiled fused epilogue: gnn conv (32->16) + d1 recompute + dense 32->2 +
// softmax. f32 NCHW store.
// ===========================================================================
__global__ __launch_bounds__(256)
void final_tiled(const float* __restrict__ cts, const bf* __restrict__ u3,
                 const bf* __restrict__ agg,
                 const float* __restrict__ w_d1, const float* __restrict__ b_d1,
                 const float* __restrict__ w_gu, const float* __restrict__ b_gu,
                 const float* __restrict__ w_de, const float* __restrict__ b_de,
                 float* __restrict__ out, int N, int tilesX)
{
    constexpr int IH = 18, IWP = 19, CHUNK = 8;
    __shared__ bf sIn[CHUNK * IH * IWP];
    __shared__ float sW[32 * 144];
    __shared__ float sDe[64];

    int tile = blockIdx.x;
    int tx0 = (tile % tilesX) * 16, ty0 = (tile / tilesX) * 16;
    int n = blockIdx.y;
    int t = threadIdx.x;
    int tx = t & 15, ty = t >> 4;

    for (int e = t; e < 32 * 144; e += 256) {
        int ci = e / 144, rem = e % 144;
        int t9 = rem / 16, co = rem % 16;
        sW[ci * 144 + t9 * 16 + co] = w_gu[(size_t)(co * 32 + ci) * 9 + t9];
    }
    if (t < 64) sDe[t] = w_de[t];

    float g[16];
    #pragma unroll
    for (int c = 0; c < 16; ++c) g[c] = b_gu[c];

    for (int cb = 0; cb < 32; cb += CHUNK) {
        __syncthreads();
        for (int e = t; e < CHUNK * IH * IH; e += 256) {
            int ci = e / (IH * IH);
            int rem = e % (IH * IH);
            int py = rem / IH, px = rem % IH;
            int iy = ty0 - 1 + py, ix = tx0 - 1 + px;
            int gci = cb + ci;
            const bf* src = (gci < 16) ? u3 + ((size_t)(n * 16 + gci) << 16)
                                       : agg + ((size_t)(n * 16 + gci - 16) << 16);
            float v = ((unsigned)iy < 256u && (unsigned)ix < 256u)
                      ? bf2f(src[(iy << 8) + ix]) : 0.f;
            sIn[ci * IH * IWP + py * IWP + px] = f2bf(v);
        }
        __syncthreads();
        for (int ci = 0; ci < CHUNK; ++ci) {
            #pragma unroll
            for (int t9 = 0; t9 < 9; ++t9) {
                int ky = t9 / 3, kx = t9 % 3;
                float v = bf2f(sIn[ci * IH * IWP + (ty + ky) * IWP + tx + kx]);
                const float* wp = &sW[(cb + ci) * 144 + t9 * 16];
                #pragma unroll
                for (int co = 0; co < 16; ++co)
                    g[co] = fmaf(v, wp[co], g[co]);
            }
        }
    }

    float l0 = b_de[0], l1 = b_de[1];
    #pragma unroll
    for (int c = 0; c < 16; ++c) {
        float v = fmaxf(g[c], 0.f);
        l0 = fmaf(v, sDe[c * 2 + 0], l0);
        l1 = fmaf(v, sDe[c * 2 + 1], l1);
    }

    int y = ty0 + ty, x = tx0 + tx;
    const float* csrc = cts + ((size_t)n << 16);
    float ct[9];
    #pragma unroll
    for (int ky = 0; ky < 3; ++ky) {
        int iy = y + ky - 1;
        #pragma unroll
        for (int kx = 0; kx < 3; ++kx) {
            int ix = x + kx - 1;
            ct[ky * 3 + kx] = ((unsigned)iy < 256u && (unsigned)ix < 256u)
                              ? csrc[(iy << 8) + ix] : 0.f;
        }
    }
    #pragma unroll
    for (int c = 0; c < 16; ++c) {
        float acc = b_d1[c];
        const float* wp = w_d1 + c * 9;
        #pragma unroll
        for (int t9 = 0; t9 < 9; ++t9) acc = fmaf(ct[t9], wp[t9], acc);
        float v = fmaxf(acc, 0.f);
        l0 = fmaf(v, sDe[(16 + c) * 2 + 0], l0);
        l1 = fmaf(v, sDe[(16 + c) * 2 + 1], l1);
    }

    float m = fmaxf(l0, l1);
    float e0 = expf(l0 - m), e1 = expf(l1 - m);
    float inv = 1.f / (e0 + e1);
    size_t base = ((size_t)n * 2) << 16;
    out[base + (y << 8) + x] = e0 * inv;
    out[base + (1 << 16) + (y << 8) + x] = e1 * inv;
}

// ===========================================================================

extern "C" void kernel_launch(void* const* d_in, const int* in_sizes, int n_in,
                              void* d_out, int out_size, void* d_ws, size_t ws_size,
                              hipStream_t stream)
{
    const float* cts  = (const float*)d_in[0];
    const int*   prng = (const int*)d_in[1];
    const float* w_d1 = (const float*)d_in[2];  const float* b_d1 = (const float*)d_in[3];
    const float* w_d2 = (const float*)d_in[4];  const float* b_d2 = (const float*)d_in[5];
    const float* w_d3 = (const float*)d_in[6];  const float* b_d3 = (const float*)d_in[7];
    const float* w_d4 = (const float*)d_in[8];  const float* b_d4 = (const float*)d_in[9];
    const float* w_u1 = (const float*)d_in[10]; const float* b_u1 = (const float*)d_in[11];
    const float* w_u2 = (const float*)d_in[12]; const float* b_u2 = (const float*)d_in[13];
    const float* w_u3 = (const float*)d_in[14]; const float* b_u3 = (const float*)d_in[15];
    const float* w_ga = (const float*)d_in[16]; const float* b_ga = (const float*)d_in[17];
    const float* w_gu = (const float*)d_in[18]; const float* b_gu = (const float*)d_in[19];
    const float* w_de = (const float*)d_in[20]; const float* b_de = (const float*)d_in[21];

    const int H = 256, Wd = 256;
    const int N = in_sizes[0] / (H * Wd);   // 32

    // ---- workspace layout (192 MiB total), lifetime reuse ----
    // U3 [+0,   64M] : u3 (persists)
    // R1 [+64M, 64M] : d1 -> u1(+0,16M), u2(+16M,32M) -> ga
    // R2 [+128M,64M] : d2(+0,32M), d3(+32M,16M), d4(+48M,8M)
    //                  -> simp(+0,16M), sim(+16M) -> agg
    // idx (384B) lives in the tail of d_out (overwritten by final_tiled).
    char* wsb = (char*)d_ws;
    bf* u3 = (bf*)(wsb);
    bf* R1 = (bf*)(wsb + 67108864);
    bf* R2 = (bf*)(wsb + 134217728);

    bf* d1 = R1;
    bf* d2 = R2;
    bf* d3 = (bf*)(wsb + 134217728 + 33554432);
    bf* d4 = (bf*)(wsb + 134217728 + 50331648);
    bf* u1 = R1;
    bf* u2 = (bf*)(wsb + 67108864 + 16777216);
    bf* ga = R1;
    bf* agg = R2;
    float* simp = (float*)R2;
    float* sim  = (float*)(wsb + 134217728 + 16777216);
    int*   idx  = (int*)d_out + (out_size - 96);

    const int KTOT = 16 * H * Wd;             // 1,048,576
    const int NCH  = KTOT / SCH;              // 4096

    // encoder
    conv_tiled<float, 1><<<dim3(256, N, 1), 256, 0, stream>>>(
        cts, (const float*)nullptr, 1, 1, w_d1, b_d1, d1, N, 256, 256, 16, 256, 256, 16);
    conv_tiled<bf, 2><<<dim3(64, N, 2), 256, 0, stream>>>(
        d1, (const bf*)nullptr, 16, 16, w_d2, b_d2, d2, N, 256, 256, 32, 128, 128, 8);
    conv_tiled<bf, 2><<<dim3(16, N, 4), 256, 0, stream>>>(
        d2, (const bf*)nullptr, 32, 32, w_d3, b_d3, d3, N, 128, 128, 64, 64, 64, 4);
    conv_tiled<bf, 2><<<dim3(4, N, 8), 256, 0, stream>>>(
        d3, (const bf*)nullptr, 64, 64, w_d4, b_d4, d4, N, 64, 64, 128, 32, 32, 2);
    // decoder
    convt_tiled<<<dim3(16, N, 4), 256, 0, stream>>>(
        d4, (const bf*)nullptr, 128, 128, w_u1, b_u1, u1, N, 32, 32, 64, 64, 64, 4);
    convt_tiled<<<dim3(64, N, 2), 256, 0, stream>>>(
        u1, d3, 64, 128, w_u2, b_u2, u2, N, 64, 64, 32, 128, 128, 8);
    convt_tiled<<<dim3(256, N, 1), 256, 0, stream>>>(
        u2, d2, 32, 64, w_u3, b_u3, u3, N, 128, 128, 16, 256, 256, 16);
    // cosine similarity + top-3
    sim_partial<<<NCH, 256, 0, stream>>>(u3, simp, KTOT);
    sim_reduce<<<dim3(N * N), 256, 0, stream>>>(simp, sim, NCH);
    topk_kernel<<<1, 64, 0, stream>>>(sim, prng, idx, N);
    // per-slice gnn-neighbor conv (once per slice), then gather-mean
    conv_tiled<bf, 1><<<dim3(256, N, 1), 256, 0, stream>>>(
        u3, (const bf*)nullptr, 16, 16, w_ga, b_ga, ga, N, 256, 256, 16, 256, 256, 16);
    gather_mean<<<dim3(512, N), 256, 0, stream>>>(ga, idx, agg);
    // fused gnn conv + d1 recompute + dense + softmax
    final_tiled<<<dim3(256, N), 256, 0, stream>>>(
        cts, u3, agg, w_d1, b_d1, w_gu, b_gu, w_de, b_de, (float*)d_out, N, 16);
}